// Round 13
// baseline (1749.640 us; speedup 1.0000x reference)
//
#include <hip/hip_runtime.h>

#define S_LEN 1024
#define BB 128
#define DD 256
#define NN 1024
#define TWO_K 512   // 2*DD
#define TWO_N 2048  // 2*NN

typedef _Float16 half8 __attribute__((ext_vector_type(8)));
typedef _Float16 half4 __attribute__((ext_vector_type(4)));
typedef float f32x4 __attribute__((ext_vector_type(4)));

__device__ __forceinline__ float wrap2pi(float x) {
  float r = fmodf(x, 6.283185307179586f);
  if (r < 0.f) r += 6.283185307179586f;
  return r;
}
__device__ __forceinline__ int lut_index(float th) {
  float w = wrap2pi(th);
  return ((int)floorf(w * 651.8986469044033f)) & 4095;
}
// quantized phase as a fraction of a revolution (exact mod-4096 in revolutions)
__device__ __forceinline__ float q12(float th) {
  const float y = floorf(th * 651.8986469044033f) * 0.000244140625f;
  return y - floorf(y);
}

// ---------------- h recurrence -> X0 [CH*BB, 2*DD] f16 interleaved ----------------
__global__ __launch_bounds__(256) void k_h(const int* __restrict__ ids,
                                           const float* __restrict__ emb,
                                           float* __restrict__ hstate,
                                           _Float16* __restrict__ X0,
                                           int t0, int CH) {
  __shared__ __align__(16) float ebuf[2][8][2][256];
  __shared__ float tphi_s[1024];
  const int tid = threadIdx.x;
  const int lane = tid & 63;
  const int wv = tid >> 6;
  for (int i = tid; i < CH; i += 256)
    tphi_s[i] = wrap2pi((float)(t0 + i) * 1.618033988749895f);

  const int b = blockIdx.x;
  const int d = tid;
  const int* __restrict__ idrow = ids + b * S_LEN + t0;
  const int NST = CH >> 3;

#pragma unroll
  for (int q = 0; q < 2; ++q) {
    const int j = wv * 2 + q;
    const int id = idrow[j];
    const float* src = emb + (size_t)id * 512 + lane * 4;
    __builtin_amdgcn_global_load_lds((const __attribute__((address_space(1))) void*)src,
                                     (__attribute__((address_space(3))) void*)(&ebuf[0][j][0][0]), 16, 0, 0);
    __builtin_amdgcn_global_load_lds((const __attribute__((address_space(1))) void*)(src + 256),
                                     (__attribute__((address_space(3))) void*)(&ebuf[0][j][1][0]), 16, 0, 0);
  }

  float hr, hi;
  if (t0 == 0) { hr = 0.f; hi = 0.f; }
  else { float2 h = ((const float2*)hstate)[b * DD + d]; hr = h.x; hi = h.y; }

  int buf = 0;
  __syncthreads();

  for (int st = 0; st < NST; ++st) {
    if (st + 1 < NST) {
#pragma unroll
      for (int q = 0; q < 2; ++q) {
        const int j = wv * 2 + q;
        const int id = idrow[(st + 1) * 8 + j];
        const float* src = emb + (size_t)id * 512 + lane * 4;
        __builtin_amdgcn_global_load_lds((const __attribute__((address_space(1))) void*)src,
                                         (__attribute__((address_space(3))) void*)(&ebuf[buf ^ 1][j][0][0]), 16, 0, 0);
        __builtin_amdgcn_global_load_lds((const __attribute__((address_space(1))) void*)(src + 256),
                                         (__attribute__((address_space(3))) void*)(&ebuf[buf ^ 1][j][1][0]), 16, 0, 0);
      }
    }
    float rwl[8], bvt[8];
#pragma unroll
    for (int j = 0; j < 8; ++j) {
      const float w  = ebuf[buf][j][0][d];
      const float bv = ebuf[buf][j][1][d];
      rwl[j] = 1.0f / (1.f + fabsf(w));
      bvt[j] = bv + tphi_s[st * 8 + j];
    }
#pragma unroll
    for (int j = 0; j < 8; ++j) {
      const int tt = st * 8 + j;
      const float thr = fmaf(hr, rwl[j], bvt[j]);
      const float thi = fmaf(hi, rwl[j], bvt[j]);
      const float fr = q12(thr);
      const float fi = q12(thi);
      const float sr = __builtin_amdgcn_sinf(fr), cr = __builtin_amdgcn_cosf(fr);
      const float si = __builtin_amdgcn_sinf(fi), ci = __builtin_amdgcn_cosf(fi);
      hr = cr * ci - sr * si;
      hi = cr * si + sr * ci;
      union { unsigned int u; _Float16 h2[2]; } pk;
      pk.h2[0] = (_Float16)hr; pk.h2[1] = (_Float16)hi;
      *(((unsigned int*)(X0 + (size_t)(tt * BB + b) * TWO_K)) + d) = pk.u;
    }
    __syncthreads();
    buf ^= 1;
  }
  ((float2*)hstate)[b * DD + d] = make_float2(hr, hi);
}

// ---------------- rotation prefix via parallel integer scan ----------------
__global__ __launch_bounds__(256) void k_rot(const float* __restrict__ omega,
                                             float2* __restrict__ C0, float2* __restrict__ D0,
                                             float2* __restrict__ D1, float2* __restrict__ C1last) {
  const int blk = blockIdx.x;               // 0..2047
  const int l = blk >> 10, n = blk & (NN - 1);
  const int tid = threadIdx.x;
  const int lane = tid & 63;
  const int wid = tid >> 6;
  const float om = omega[l * NN + n];

  int pre[4];
  int own = 0;
  const int tb = tid * 4;
#pragma unroll
  for (int j = 0; j < 4; ++j) {
    own += lut_index(om + (float)(tb + j) * 1.618033988749895f);
    pre[j] = own;
  }
  int v = own;
#pragma unroll
  for (int off = 1; off < 64; off <<= 1) {
    int u = __shfl_up(v, off);
    if (lane >= off) v += u;
  }
  __shared__ int wsum[4];
  if (lane == 63) wsum[wid] = v;
  __syncthreads();
  int woff = 0;
#pragma unroll
  for (int w = 0; w < 4; ++w) woff += (w < wid) ? wsum[w] : 0;
  const int excl = woff + v - own;

#pragma unroll
  for (int j = 0; j < 4; ++j) {
    const int t = tb + j;
    const int idx = (excl + pre[j]) & 4095;
    const float s = sinf(0.0015339807878856412f * (float)idx);
    const float c = cosf(0.0015339807878856412f * (float)idx);
    if (l == 0) {
      C0[t * NN + n] = make_float2(c, s);
      D0[t * NN + n] = make_float2(c, -s);
    } else {
      D1[t * NN + n] = make_float2(c, -s);
      if (t == S_LEN - 1) C1last[n] = make_float2(c, s);
    }
  }
}

// ---------------- f16 MFMA GEMM: 128x256 tile (BM=128, BN=256), BK=64, single LDS buffer ----------------
// A [M,K] f16, BT [N,K] f16, C [M,N] f16. 256 threads = 4 waves (2x2), per-wave 64x128 out
// (two 64x64 col-subtiles ct=0,1). One A-tile + two B-subtiles staged per K-step ->
// 64 MFMA/wave per barrier pair (2x the 128x128 version), ds_read/MFMA down 25%,
// A re-fetch across col-blocks halved. Accumulation order per output element unchanged
// vs the 128x128 kernel -> bit-identical C.
__global__ __launch_bounds__(256, 2) void k_gemm(const _Float16* __restrict__ A,
                                                 const _Float16* __restrict__ BT,
                                                 _Float16* __restrict__ C,
                                                 int M, int N, int K, int nxlog2,
                                                 const float2* __restrict__ rot) {
  __shared__ __align__(16) _Float16 As[128 * 64];        // 16 KB
  __shared__ __align__(16) _Float16 Bs[2][128 * 64];     // 32 KB
  const int tid = threadIdx.x;
  const int lane = tid & 63;
  const int wave = tid >> 6;
  const int wm = wave >> 1;
  const int wn = wave & 1;

  const int cpx = gridDim.x >> 3;
  const int bid = blockIdx.x;
  const int swz = (bid & 7) * cpx + (bid >> 3);
  const int bx = swz & ((1 << nxlog2) - 1);
  const int by = swz >> nxlog2;
  const int m0 = by * 128;
  const int n0 = bx * 256;

  const int srow = lane >> 3;               // row within 8-row chunk
  const int schunk = (lane & 7) ^ srow;     // XOR-swizzled source 16B-chunk

  f32x4 acc[2][4][4] = {};

  for (int kt = 0; kt < K; kt += 64) {
#pragma unroll
    for (int j = 0; j < 4; ++j) {
      const int c = wave * 4 + j;           // chunk 0..15, covers rows c*8..c*8+7
      const int row = c * 8 + srow;
      const _Float16* srcA = A + (size_t)(m0 + row) * K + kt + schunk * 8;
      __builtin_amdgcn_global_load_lds((const __attribute__((address_space(1))) void*)srcA,
                                       (__attribute__((address_space(3))) void*)(As + c * 512), 16, 0, 0);
      const _Float16* srcB0 = BT + (size_t)(n0 + row) * K + kt + schunk * 8;
      __builtin_amdgcn_global_load_lds((const __attribute__((address_space(1))) void*)srcB0,
                                       (__attribute__((address_space(3))) void*)(&Bs[0][0] + c * 512), 16, 0, 0);
      const _Float16* srcB1 = BT + (size_t)(n0 + 128 + row) * K + kt + schunk * 8;
      __builtin_amdgcn_global_load_lds((const __attribute__((address_space(1))) void*)srcB1,
                                       (__attribute__((address_space(3))) void*)(&Bs[1][0] + c * 512), 16, 0, 0);
    }
    __syncthreads();
#pragma unroll
    for (int ks = 0; ks < 2; ++ks) {
      half8 af[4];
#pragma unroll
      for (int mr = 0; mr < 4; ++mr) {
        const int ar = wm * 64 + mr * 16 + (lane & 15);
        const int p = ((ks * 4) + (lane >> 4)) ^ (ar & 7);
        af[mr] = *(const half8*)(As + ar * 64 + p * 8);
      }
#pragma unroll
      for (int ct = 0; ct < 2; ++ct) {
        half8 bf[4];
#pragma unroll
        for (int nr = 0; nr < 4; ++nr) {
          const int br = wn * 64 + nr * 16 + (lane & 15);
          const int p = ((ks * 4) + (lane >> 4)) ^ (br & 7);
          bf[nr] = *(const half8*)(&Bs[ct][0] + br * 64 + p * 8);
        }
#pragma unroll
        for (int mr = 0; mr < 4; ++mr)
#pragma unroll
          for (int nr = 0; nr < 4; ++nr)
            acc[ct][mr][nr] = __builtin_amdgcn_mfma_f32_16x16x32_f16(af[mr], bf[nr], acc[ct][mr][nr], 0, 0, 0);
      }
    }
    __syncthreads();
  }

  const int halfN = N >> 1;
  const int t = by;                          // BM == BB: one row-block == one t
#pragma unroll
  for (int ct = 0; ct < 2; ++ct)
#pragma unroll
    for (int mr = 0; mr < 4; ++mr)
#pragma unroll
      for (int nr = 0; nr < 4; ++nr) {
        const int col = n0 + ct * 128 + wn * 64 + nr * 16 + (lane & 15);
        const int rbase = m0 + wm * 64 + mr * 16 + ((lane >> 4) << 2);
        float2 dr = make_float2(1.f, 0.f);
        if (rot) dr = rot[(size_t)t * halfN + (col >> 1)];
#pragma unroll
        for (int j = 0; j < 4; ++j) {
          float v = acc[ct][mr][nr][j];
          if (rot) {
            const float pv = __shfl_xor(v, 1);
            v = (lane & 1) ? (dr.x * v + dr.y * pv) : (dr.x * v - dr.y * pv);
          }
          C[(size_t)(rbase + j) * N + col] = (_Float16)v;
        }
      }
}

// ---------------- prefix-sum over t (in place), then multiply by C0[t] ----------------
#define SUF 8
__global__ __launch_bounds__(256) void k_scan(_Float16* __restrict__ V,
                                              const float2* __restrict__ C0c,
                                              float2* __restrict__ ZS, int CH, int first) {
  const int gid = blockIdx.x * 256 + threadIdx.x;
  const int npair = gid & (NN / 2 - 1);
  const int b = gid >> 9;
  const int n = npair * 2;
  float zr0, zi0, zr1, zi1;
  if (first) { zr0 = zi0 = zr1 = zi1 = 0.f; }
  else {
    float4 z = *(const float4*)(ZS + (size_t)b * NN + n);
    zr0 = z.x; zi0 = z.y; zr1 = z.z; zi1 = z.w;
  }
  uint2 vb[SUF], vn[SUF];
  float4 cb[SUF], cn[SUF];
#pragma unroll
  for (int j = 0; j < SUF; ++j) {
    vb[j] = *(const uint2*)(((const unsigned int*)(V + (size_t)(j * BB + b) * TWO_N)) + n);
    cb[j] = *(const float4*)(C0c + (size_t)j * NN + n);
  }
  for (int st = 0; st < CH; st += SUF) {
    const bool more = (st + SUF) < CH;
    if (more) {
#pragma unroll
      for (int j = 0; j < SUF; ++j) {
        vn[j] = *(const uint2*)(((const unsigned int*)(V + (size_t)((st + SUF + j) * BB + b) * TWO_N)) + n);
        cn[j] = *(const float4*)(C0c + (size_t)(st + SUF + j) * NN + n);
      }
    }
#pragma unroll
    for (int j = 0; j < SUF; ++j) {
      union { unsigned int u; _Float16 h2[2]; } a, c;
      a.u = vb[j].x; c.u = vb[j].y;
      zr0 += (float)a.h2[0]; zi0 += (float)a.h2[1];
      zr1 += (float)c.h2[0]; zi1 += (float)c.h2[1];
      const float4 cc = cb[j];
      a.h2[0] = (_Float16)(cc.x * zr0 - cc.y * zi0);
      a.h2[1] = (_Float16)(cc.x * zi0 + cc.y * zr0);
      c.h2[0] = (_Float16)(cc.z * zr1 - cc.w * zi1);
      c.h2[1] = (_Float16)(cc.z * zi1 + cc.w * zr1);
      *(uint2*)(((unsigned int*)(V + (size_t)((st + j) * BB + b) * TWO_N)) + n) = make_uint2(a.u, c.u);
    }
#pragma unroll
    for (int j = 0; j < SUF; ++j) { vb[j] = vn[j]; cb[j] = cn[j]; }
  }
  *(float4*)(ZS + (size_t)b * NN + n) = make_float4(zr0, zi0, zr1, zi1);
}

// ---------------- reduce over t ----------------
__global__ __launch_bounds__(256) void k_reduce(const _Float16* __restrict__ U,
                                                float* __restrict__ s1, int CH, int first) {
  const int gid = blockIdx.x * 256 + threadIdx.x;
  const int g = gid & (TWO_N / 4 - 1);
  const int b = gid >> 9;
  const int np = g * 4;
  f32x4 acc;
  if (first) {
#pragma unroll
    for (int j = 0; j < 4; ++j) acc[j] = 0.f;
  } else {
    acc = *(const f32x4*)(s1 + (size_t)b * TWO_N + np);
  }
  half4 vb[SUF], vn[SUF];
#pragma unroll
  for (int j = 0; j < SUF; ++j)
    vb[j] = *(const half4*)(U + (size_t)(j * BB + b) * TWO_N + np);
  for (int st = 0; st < CH; st += SUF) {
    const bool more = (st + SUF) < CH;
    if (more) {
#pragma unroll
      for (int j = 0; j < SUF; ++j)
        vn[j] = *(const half4*)(U + (size_t)((st + SUF + j) * BB + b) * TWO_N + np);
    }
#pragma unroll
    for (int j = 0; j < SUF; ++j) {
#pragma unroll
      for (int q = 0; q < 4; ++q) acc[q] += (float)vb[j][q];
    }
#pragma unroll
    for (int j = 0; j < SUF; ++j) vb[j] = vn[j];
  }
  *(f32x4*)(s1 + (size_t)b * TWO_N + np) = acc;
}

// ---------------- tail GEMM 1: xt = rot(s1) @ Wout1, rotation fused into A-load ----------------
__global__ __launch_bounds__(256) void k_tail1(const float* __restrict__ s1,
                                               const float2* __restrict__ C1last,
                                               const float* __restrict__ BT,   // [TWO_K, TWO_N]
                                               float* __restrict__ C) {
  const int wave = threadIdx.x >> 6;
  const int lane = threadIdx.x & 63;
  const int o = blockIdx.x * 4 + wave;     // 0 .. 128*512
  const int row = o >> 9;                  // / TWO_K
  const int col = o & (TWO_K - 1);
  const float4* __restrict__ a4 = (const float4*)(s1 + (size_t)row * TWO_N);
  const float4* __restrict__ c4 = (const float4*)C1last;
  const float4* __restrict__ b4 = (const float4*)(BT + (size_t)col * TWO_N);
  float acc = 0.f;
#pragma unroll
  for (int it = 0; it < 8; ++it) {
    const int idx = it * 64 + lane;
    const float4 av = a4[idx];
    const float4 cc = c4[idx];
    const float4 bv = b4[idx];
    const float r0 = cc.x * av.x - cc.y * av.y;
    const float i0 = cc.x * av.y + cc.y * av.x;
    const float r1 = cc.z * av.z - cc.w * av.w;
    const float i1 = cc.z * av.w + cc.w * av.z;
    acc = fmaf(r0, bv.x, acc);
    acc = fmaf(i0, bv.y, acc);
    acc = fmaf(r1, bv.z, acc);
    acc = fmaf(i1, bv.w, acc);
  }
#pragma unroll
  for (int s = 32; s >= 1; s >>= 1) acc += __shfl_xor(acc, s);
  if (lane == 0) C[o] = acc;
}

// ---------------- tail GEMM: one wave per output, A [M,K] f32, BT [N,K] f32 ----------------
__global__ __launch_bounds__(256) void k_tail(const float* __restrict__ A,
                                              const float* __restrict__ BT,
                                              float* __restrict__ C, int M, int N, int K) {
  const int wave = threadIdx.x >> 6;
  const int lane = threadIdx.x & 63;
  const int o = blockIdx.x * 4 + wave;
  if (o >= M * N) return;
  const int row = o / N;
  const int col = o - row * N;
  const float4* __restrict__ a4 = (const float4*)(A + (size_t)row * K);
  const float4* __restrict__ b4 = (const float4*)(BT + (size_t)col * K);
  float acc = 0.f;
  const int nit = K >> 8;
  for (int it = 0; it < nit; ++it) {
    const float4 av = a4[it * 64 + lane];
    const float4 bv = b4[it * 64 + lane];
    acc = fmaf(av.x, bv.x, acc);
    acc = fmaf(av.y, bv.y, acc);
    acc = fmaf(av.z, bv.z, acc);
    acc = fmaf(av.w, bv.w, acc);
  }
#pragma unroll
  for (int s = 32; s >= 1; s >>= 1) acc += __shfl_xor(acc, s);
  if (lane == 0) C[o] = acc;
}

// ---------------- weight packing ----------------
__global__ __launch_bounds__(256) void k_prep_in(const float* __restrict__ r, const float* __restrict__ im,
                                                 _Float16* __restrict__ dst) {
  const int gid = blockIdx.x * 256 + threadIdx.x;
  const int n = gid & (NN - 1);
  const int k = gid >> 10;
  const float rv = r[(size_t)k * NN + n], iv = im[(size_t)k * NN + n];
  const size_t base = (size_t)(2 * n) * TWO_K + 2 * k;
  dst[base] = (_Float16)rv;              dst[base + 1] = (_Float16)(-iv);
  dst[base + TWO_K] = (_Float16)iv;      dst[base + TWO_K + 1] = (_Float16)rv;
}
__global__ __launch_bounds__(256) void k_prep_out(const float* __restrict__ r, const float* __restrict__ im,
                                                  _Float16* __restrict__ dst) {
  const int gid = blockIdx.x * 256 + threadIdx.x;
  const int d = gid & (DD - 1);
  const int n = gid >> 8;
  const float rv = r[(size_t)n * DD + d], iv = im[(size_t)n * DD + d];
  const size_t base = (size_t)(2 * d) * TWO_N + 2 * n;
  dst[base] = (_Float16)rv;              dst[base + 1] = (_Float16)(-iv);
  dst[base + TWO_N] = (_Float16)iv;      dst[base + TWO_N + 1] = (_Float16)rv;
}
__global__ __launch_bounds__(256) void k_prep_wout1T(const float* __restrict__ r, const float* __restrict__ im,
                                                     float* __restrict__ dstT) {
  const int gid = blockIdx.x * 256 + threadIdx.x;
  const int n = gid & (NN - 1);
  const int d = gid >> 10;
  const float rv = r[(size_t)n * DD + d], iv = im[(size_t)n * DD + d];
  const size_t b0 = (size_t)(2 * d) * TWO_N + 2 * n;
  const size_t b1 = (size_t)(2 * d + 1) * TWO_N + 2 * n;
  dstT[b0] = rv;     dstT[b0 + 1] = -iv;
  dstT[b1] = iv;     dstT[b1 + 1] = rv;
}
__global__ __launch_bounds__(256) void k_prep_finT(const float* __restrict__ pr, const float* __restrict__ pi_,
                                                   float* __restrict__ dstT) {
  const int gid = blockIdx.x * 256 + threadIdx.x;
  const int d = gid & (DD - 1);
  const int s = gid >> 8;
  const float a = pr[(size_t)d * 256 + s], b = pi_[(size_t)d * 256 + s];
  dstT[(size_t)s * TWO_K + 2 * d] = a + b;
  dstT[(size_t)s * TWO_K + 2 * d + 1] = a - b;
}

extern "C" void kernel_launch(void* const* d_in, const int* in_sizes, int n_in,
                              void* d_out, int out_size, void* d_ws, size_t ws_size,
                              hipStream_t stream) {
  const int* ids      = (const int*)d_in[0];
  const float* emb    = (const float*)d_in[1];
  const float* win_r  = (const float*)d_in[2];
  const float* win_i  = (const float*)d_in[3];
  const float* wout_r = (const float*)d_in[4];
  const float* wout_i = (const float*)d_in[5];
  const float* omega  = (const float*)d_in[6];
  const float* outp_r = (const float*)d_in[7];
  const float* outp_i = (const float*)d_in[8];

  char* ws = (char*)d_ws;
  size_t off = 0;
  auto alloc = [&](size_t bytes) { void* p = ws + off; off += (bytes + 255) & ~(size_t)255; return p; };

  float2* C0     = (float2*)alloc((size_t)S_LEN * NN * 8);
  float2* D0     = (float2*)alloc((size_t)S_LEN * NN * 8);
  float2* D1     = (float2*)alloc((size_t)S_LEN * NN * 8);
  float2* C1last = (float2*)alloc((size_t)NN * 8);
  float2* ZS     = (float2*)alloc((size_t)BB * NN * 8);
  float* hstate  = (float*)alloc((size_t)BB * DD * 2 * 4);
  float* s1      = (float*)alloc((size_t)BB * TWO_N * 4);
  float* xt      = (float*)alloc((size_t)BB * TWO_K * 4);
  _Float16* BTin0  = (_Float16*)alloc((size_t)TWO_N * TWO_K * 2);
  _Float16* BTout0 = (_Float16*)alloc((size_t)TWO_K * TWO_N * 2);
  _Float16* BTin1  = (_Float16*)alloc((size_t)TWO_N * TWO_K * 2);
  float* Wout1T = (float*)alloc((size_t)TWO_K * TWO_N * 4);
  float* WfinT  = (float*)alloc((size_t)256 * TWO_K * 4);
  const size_t fixed = off;

  int CH = 1024;
  while (CH > 32) {
    size_t need = fixed + (size_t)CH * BB * 2 * (TWO_K + TWO_N) + 2 * 256;
    if (need <= ws_size) break;
    CH >>= 1;
  }
  _Float16* X0 = (_Float16*)alloc((size_t)CH * BB * TWO_K * 2);
  _Float16* VB = (_Float16*)alloc((size_t)CH * BB * TWO_N * 2);
  _Float16* Yc = X0;

  k_rot<<<2 * NN, 256, 0, stream>>>(omega, C0, D0, D1, C1last);
  k_prep_in<<<DD * NN / 256, 256, 0, stream>>>(win_r, win_i, BTin0);
  k_prep_in<<<DD * NN / 256, 256, 0, stream>>>(win_r + (size_t)DD * NN, win_i + (size_t)DD * NN, BTin1);
  k_prep_out<<<NN * DD / 256, 256, 0, stream>>>(wout_r, wout_i, BTout0);
  k_prep_wout1T<<<NN * DD / 256, 256, 0, stream>>>(wout_r + (size_t)NN * DD, wout_i + (size_t)NN * DD, Wout1T);
  k_prep_finT<<<DD * 256 / 256, 256, 0, stream>>>(outp_r, outp_i, WfinT);

  const int nchunks = S_LEN / CH;
  for (int c = 0; c < nchunks; ++c) {
    const int t0 = c * CH;
    const int M = CH * BB;
    k_h<<<BB, 256, 0, stream>>>(ids, emb, hstate, X0, t0, CH);
    const int nb1 = (M / 128) * (TWO_N / 256);   // 256*8 = 2048, % 8 == 0
    k_gemm<<<nb1, 256, 0, stream>>>(X0, BTin0, VB, M, TWO_N, TWO_K, 3, D0 + (size_t)t0 * NN);
    k_scan<<<BB * (NN / 2) / 256, 256, 0, stream>>>(VB, C0 + (size_t)t0 * NN, ZS, CH, c == 0);
    const int nb2 = (M / 128) * (TWO_K / 256);   // 256*2 = 512, % 8 == 0
    k_gemm<<<nb2, 256, 0, stream>>>(VB, BTout0, Yc, M, TWO_K, TWO_N, 1, nullptr);
    k_gemm<<<nb1, 256, 0, stream>>>(Yc, BTin1, VB, M, TWO_N, TWO_K, 3, D1 + (size_t)t0 * NN);
    k_reduce<<<BB * (TWO_N / 4) / 256, 256, 0, stream>>>(VB, s1, CH, c == 0);
  }

  // xt[128, 512] = (C1last (*) s1) @ Wout1   (rotation fused into A-load)
  k_tail1<<<BB * TWO_K / 4, 256, 0, stream>>>(s1, C1last, Wout1T, xt);
  // out[128, 256] = xt[128, 512] @ Wfin
  k_tail<<<BB * 256 / 4, 256, 0, stream>>>(xt, WfinT, (float*)d_out, BB, 256, TWO_K);
}

// Round 14
// 1492.125 us; speedup vs baseline: 1.1726x; 1.1726x over previous
//
#include <hip/hip_runtime.h>

#define S_LEN 1024
#define BB 128
#define DD 256
#define NN 1024
#define TWO_K 512   // 2*DD
#define TWO_N 2048  // 2*NN

typedef _Float16 half8 __attribute__((ext_vector_type(8)));
typedef _Float16 half4 __attribute__((ext_vector_type(4)));
typedef float f32x4 __attribute__((ext_vector_type(4)));

__device__ __forceinline__ float wrap2pi(float x) {
  float r = fmodf(x, 6.283185307179586f);
  if (r < 0.f) r += 6.283185307179586f;
  return r;
}
__device__ __forceinline__ int lut_index(float th) {
  float w = wrap2pi(th);
  return ((int)floorf(w * 651.8986469044033f)) & 4095;
}
// quantized phase as a fraction of a revolution (exact mod-4096 in revolutions)
__device__ __forceinline__ float q12(float th) {
  const float y = floorf(th * 651.8986469044033f) * 0.000244140625f;
  return y - floorf(y);
}

// ---------------- h recurrence -> X0 [CH*BB, 2*DD] f16 interleaved ----------------
__global__ __launch_bounds__(256) void k_h(const int* __restrict__ ids,
                                           const float* __restrict__ emb,
                                           float* __restrict__ hstate,
                                           _Float16* __restrict__ X0,
                                           int t0, int CH) {
  __shared__ __align__(16) float ebuf[2][8][2][256];
  __shared__ float tphi_s[1024];
  const int tid = threadIdx.x;
  const int lane = tid & 63;
  const int wv = tid >> 6;
  for (int i = tid; i < CH; i += 256)
    tphi_s[i] = wrap2pi((float)(t0 + i) * 1.618033988749895f);

  const int b = blockIdx.x;
  const int d = tid;
  const int* __restrict__ idrow = ids + b * S_LEN + t0;
  const int NST = CH >> 3;

#pragma unroll
  for (int q = 0; q < 2; ++q) {
    const int j = wv * 2 + q;
    const int id = idrow[j];
    const float* src = emb + (size_t)id * 512 + lane * 4;
    __builtin_amdgcn_global_load_lds((const __attribute__((address_space(1))) void*)src,
                                     (__attribute__((address_space(3))) void*)(&ebuf[0][j][0][0]), 16, 0, 0);
    __builtin_amdgcn_global_load_lds((const __attribute__((address_space(1))) void*)(src + 256),
                                     (__attribute__((address_space(3))) void*)(&ebuf[0][j][1][0]), 16, 0, 0);
  }

  float hr, hi;
  if (t0 == 0) { hr = 0.f; hi = 0.f; }
  else { float2 h = ((const float2*)hstate)[b * DD + d]; hr = h.x; hi = h.y; }

  int buf = 0;
  __syncthreads();

  for (int st = 0; st < NST; ++st) {
    if (st + 1 < NST) {
#pragma unroll
      for (int q = 0; q < 2; ++q) {
        const int j = wv * 2 + q;
        const int id = idrow[(st + 1) * 8 + j];
        const float* src = emb + (size_t)id * 512 + lane * 4;
        __builtin_amdgcn_global_load_lds((const __attribute__((address_space(1))) void*)src,
                                         (__attribute__((address_space(3))) void*)(&ebuf[buf ^ 1][j][0][0]), 16, 0, 0);
        __builtin_amdgcn_global_load_lds((const __attribute__((address_space(1))) void*)(src + 256),
                                         (__attribute__((address_space(3))) void*)(&ebuf[buf ^ 1][j][1][0]), 16, 0, 0);
      }
    }
    float rwl[8], bvt[8];
#pragma unroll
    for (int j = 0; j < 8; ++j) {
      const float w  = ebuf[buf][j][0][d];
      const float bv = ebuf[buf][j][1][d];
      rwl[j] = 1.0f / (1.f + fabsf(w));
      bvt[j] = bv + tphi_s[st * 8 + j];
    }
#pragma unroll
    for (int j = 0; j < 8; ++j) {
      const int tt = st * 8 + j;
      const float thr = fmaf(hr, rwl[j], bvt[j]);
      const float thi = fmaf(hi, rwl[j], bvt[j]);
      const float fr = q12(thr);
      const float fi = q12(thi);
      const float sr = __builtin_amdgcn_sinf(fr), cr = __builtin_amdgcn_cosf(fr);
      const float si = __builtin_amdgcn_sinf(fi), ci = __builtin_amdgcn_cosf(fi);
      hr = cr * ci - sr * si;
      hi = cr * si + sr * ci;
      union { unsigned int u; _Float16 h2[2]; } pk;
      pk.h2[0] = (_Float16)hr; pk.h2[1] = (_Float16)hi;
      *(((unsigned int*)(X0 + (size_t)(tt * BB + b) * TWO_K)) + d) = pk.u;
    }
    __syncthreads();
    buf ^= 1;
  }
  ((float2*)hstate)[b * DD + d] = make_float2(hr, hi);
}

// ---------------- rotation tables ----------------
// l==0: R0[t,n] = per-step rotation (cos, sin) of quantized angle(omega0 + t*PHI)
//       (scan applies w_t = r_t (*) w_{t-1} + u_t — the original recurrence).
// l==1: D1[t,n] = conj of prefix rotation (for fused reduce); C1last[n] = full-prefix rotation.
__global__ __launch_bounds__(256) void k_rot(const float* __restrict__ omega,
                                             float2* __restrict__ R0, float2* __restrict__ D1,
                                             float2* __restrict__ C1last) {
  const int blk = blockIdx.x;               // 0..2047
  const int l = blk >> 10, n = blk & (NN - 1);
  const int tid = threadIdx.x;
  const int lane = tid & 63;
  const int wid = tid >> 6;
  const float om = omega[l * NN + n];

  int idxv[4], pre[4];
  int own = 0;
  const int tb = tid * 4;
#pragma unroll
  for (int j = 0; j < 4; ++j) {
    idxv[j] = lut_index(om + (float)(tb + j) * 1.618033988749895f);
    own += idxv[j];
    pre[j] = own;
  }
  if (l == 0) {
#pragma unroll
    for (int j = 0; j < 4; ++j) {
      const int t = tb + j;
      const float s = sinf(0.0015339807878856412f * (float)idxv[j]);
      const float c = cosf(0.0015339807878856412f * (float)idxv[j]);
      R0[t * NN + n] = make_float2(c, s);
    }
    return;  // block-uniform (l per block) — safe before barrier
  }
  int v = own;
#pragma unroll
  for (int off = 1; off < 64; off <<= 1) {
    int u = __shfl_up(v, off);
    if (lane >= off) v += u;
  }
  __shared__ int wsum[4];
  if (lane == 63) wsum[wid] = v;
  __syncthreads();
  int woff = 0;
#pragma unroll
  for (int w = 0; w < 4; ++w) woff += (w < wid) ? wsum[w] : 0;
  const int excl = woff + v - own;

#pragma unroll
  for (int j = 0; j < 4; ++j) {
    const int t = tb + j;
    const int idx = (excl + pre[j]) & 4095;
    const float s = sinf(0.0015339807878856412f * (float)idx);
    const float c = cosf(0.0015339807878856412f * (float)idx);
    D1[t * NN + n] = make_float2(c, -s);
    if (t == S_LEN - 1) C1last[n] = make_float2(c, s);
  }
}

// ---------------- f16 MFMA GEMM (R8/R12 structure): 128x128 tile, BK=64, pure (no epilogue rot) ----------------
__global__ __launch_bounds__(256, 2) void k_gemm(const _Float16* __restrict__ A,
                                                 const _Float16* __restrict__ BT,
                                                 _Float16* __restrict__ C,
                                                 int M, int N, int K, int nxlog2) {
  __shared__ __align__(16) _Float16 As[128 * 64];
  __shared__ __align__(16) _Float16 Bs[128 * 64];
  const int tid = threadIdx.x;
  const int lane = tid & 63;
  const int wave = tid >> 6;
  const int wm = wave >> 1;
  const int wn = wave & 1;

  const int cpx = gridDim.x >> 3;
  const int bid = blockIdx.x;
  const int swz = (bid & 7) * cpx + (bid >> 3);
  const int bx = swz & ((1 << nxlog2) - 1);
  const int by = swz >> nxlog2;
  const int m0 = by * 128;
  const int n0 = bx * 128;

  const int srow = lane >> 3;               // row within 8-row chunk
  const int schunk = (lane & 7) ^ srow;     // XOR-swizzled source 16B-chunk

  f32x4 acc[4][4] = {};

  for (int kt = 0; kt < K; kt += 64) {
#pragma unroll
    for (int j = 0; j < 4; ++j) {
      const int c = wave * 4 + j;           // chunk 0..15, covers rows c*8..c*8+7
      const int row = c * 8 + srow;
      const _Float16* srcA = A + (size_t)(m0 + row) * K + kt + schunk * 8;
      __builtin_amdgcn_global_load_lds((const __attribute__((address_space(1))) void*)srcA,
                                       (__attribute__((address_space(3))) void*)(As + c * 512), 16, 0, 0);
      const _Float16* srcB = BT + (size_t)(n0 + row) * K + kt + schunk * 8;
      __builtin_amdgcn_global_load_lds((const __attribute__((address_space(1))) void*)srcB,
                                       (__attribute__((address_space(3))) void*)(Bs + c * 512), 16, 0, 0);
    }
    __syncthreads();
#pragma unroll
    for (int ks = 0; ks < 2; ++ks) {
      half8 af[4], bf[4];
#pragma unroll
      for (int mr = 0; mr < 4; ++mr) {
        const int ar = wm * 64 + mr * 16 + (lane & 15);
        const int p = ((ks * 4) + (lane >> 4)) ^ (ar & 7);
        af[mr] = *(const half8*)(As + ar * 64 + p * 8);
      }
#pragma unroll
      for (int nr = 0; nr < 4; ++nr) {
        const int br = wn * 64 + nr * 16 + (lane & 15);
        const int p = ((ks * 4) + (lane >> 4)) ^ (br & 7);
        bf[nr] = *(const half8*)(Bs + br * 64 + p * 8);
      }
#pragma unroll
      for (int mr = 0; mr < 4; ++mr)
#pragma unroll
        for (int nr = 0; nr < 4; ++nr)
          acc[mr][nr] = __builtin_amdgcn_mfma_f32_16x16x32_f16(af[mr], bf[nr], acc[mr][nr], 0, 0, 0);
    }
    __syncthreads();
  }

#pragma unroll
  for (int mr = 0; mr < 4; ++mr)
#pragma unroll
    for (int nr = 0; nr < 4; ++nr) {
      const int col = n0 + wn * 64 + nr * 16 + (lane & 15);
      const int rbase = m0 + wm * 64 + mr * 16 + ((lane >> 4) << 2);
#pragma unroll
      for (int j = 0; j < 4; ++j)
        C[(size_t)(rbase + j) * N + col] = (_Float16)acc[mr][nr][j];
    }
}

// ---------------- recurrence scan over t (in place): w_t = r_t (*) w_{t-1} + u_t ----------------
#define SUF 8
__global__ __launch_bounds__(256) void k_scan(_Float16* __restrict__ V,          // [CH*BB, TWO_N]
                                              const float2* __restrict__ R0c,    // [CH, NN] at t0
                                              float2* __restrict__ ZS, int CH, int first) {
  const int gid = blockIdx.x * 256 + threadIdx.x;
  const int npair = gid & (NN / 2 - 1);
  const int b = gid >> 9;
  const int n = npair * 2;
  float zr0, zi0, zr1, zi1;
  if (first) { zr0 = zi0 = zr1 = zi1 = 0.f; }
  else {
    float4 z = *(const float4*)(ZS + (size_t)b * NN + n);
    zr0 = z.x; zi0 = z.y; zr1 = z.z; zi1 = z.w;
  }
  const float4* __restrict__ r4 = (const float4*)R0c;
  uint2 vb[SUF], vn[SUF];
  float4 cb[SUF], cn[SUF];
#pragma unroll
  for (int j = 0; j < SUF; ++j) {
    vb[j] = *(const uint2*)(((const unsigned int*)(V + (size_t)(j * BB + b) * TWO_N)) + n);
    cb[j] = r4[(size_t)j * (NN / 2) + npair];
  }
  for (int st = 0; st < CH; st += SUF) {
    const bool more = (st + SUF) < CH;
    if (more) {
#pragma unroll
      for (int j = 0; j < SUF; ++j) {
        vn[j] = *(const uint2*)(((const unsigned int*)(V + (size_t)((st + SUF + j) * BB + b) * TWO_N)) + n);
        cn[j] = r4[(size_t)(st + SUF + j) * (NN / 2) + npair];
      }
    }
#pragma unroll
    for (int j = 0; j < SUF; ++j) {
      union { unsigned int u; _Float16 h2[2]; } a, c;
      a.u = vb[j].x; c.u = vb[j].y;
      const float4 cc = cb[j];
      const float w0r = cc.x * zr0 - cc.y * zi0 + (float)a.h2[0];
      const float w0i = cc.x * zi0 + cc.y * zr0 + (float)a.h2[1];
      const float w1r = cc.z * zr1 - cc.w * zi1 + (float)c.h2[0];
      const float w1i = cc.z * zi1 + cc.w * zr1 + (float)c.h2[1];
      zr0 = w0r; zi0 = w0i; zr1 = w1r; zi1 = w1i;
      a.h2[0] = (_Float16)zr0; a.h2[1] = (_Float16)zi0;
      c.h2[0] = (_Float16)zr1; c.h2[1] = (_Float16)zi1;
      *(uint2*)(((unsigned int*)(V + (size_t)((st + j) * BB + b) * TWO_N)) + n) = make_uint2(a.u, c.u);
    }
#pragma unroll
    for (int j = 0; j < SUF; ++j) { vb[j] = vn[j]; cb[j] = cn[j]; }
  }
  *(float4*)(ZS + (size_t)b * NN + n) = make_float4(zr0, zi0, zr1, zi1);
}

// ---------------- fused rotate+reduce over t: s1 += D1[t] (*) u[t] ----------------
__global__ __launch_bounds__(256) void k_reduce(const _Float16* __restrict__ U,  // [CH*BB, TWO_N]
                                                const float2* __restrict__ D1c, // [CH, NN] at t0
                                                float* __restrict__ s1, int CH, int first) {
  const int gid = blockIdx.x * 256 + threadIdx.x;
  const int g = gid & (TWO_N / 4 - 1);      // 0..511: 2 complex per thread
  const int b = gid >> 9;
  const int np = g * 4;
  f32x4 acc;
  if (first) {
#pragma unroll
    for (int j = 0; j < 4; ++j) acc[j] = 0.f;
  } else {
    acc = *(const f32x4*)(s1 + (size_t)b * TWO_N + np);
  }
  const float4* __restrict__ d4 = (const float4*)D1c;
  half4 vb[SUF], vn[SUF];
  float4 db[SUF], dn[SUF];
#pragma unroll
  for (int j = 0; j < SUF; ++j) {
    vb[j] = *(const half4*)(U + (size_t)(j * BB + b) * TWO_N + np);
    db[j] = d4[(size_t)j * (NN / 2) + g];
  }
  for (int st = 0; st < CH; st += SUF) {
    const bool more = (st + SUF) < CH;
    if (more) {
#pragma unroll
      for (int j = 0; j < SUF; ++j) {
        vn[j] = *(const half4*)(U + (size_t)((st + SUF + j) * BB + b) * TWO_N + np);
        dn[j] = d4[(size_t)(st + SUF + j) * (NN / 2) + g];
      }
    }
#pragma unroll
    for (int j = 0; j < SUF; ++j) {
      const float u0 = (float)vb[j][0], u1 = (float)vb[j][1];
      const float u2 = (float)vb[j][2], u3 = (float)vb[j][3];
      const float4 d = db[j];
      acc[0] += d.x * u0 - d.y * u1;
      acc[1] += d.x * u1 + d.y * u0;
      acc[2] += d.z * u2 - d.w * u3;
      acc[3] += d.z * u3 + d.w * u2;
    }
#pragma unroll
    for (int j = 0; j < SUF; ++j) { vb[j] = vn[j]; db[j] = dn[j]; }
  }
  *(f32x4*)(s1 + (size_t)b * TWO_N + np) = acc;
}

// ---------------- tail GEMM 1: xt = rot(s1) @ Wout1, rotation fused into A-load ----------------
__global__ __launch_bounds__(256) void k_tail1(const float* __restrict__ s1,
                                               const float2* __restrict__ C1last,
                                               const float* __restrict__ BT,   // [TWO_K, TWO_N]
                                               float* __restrict__ C) {
  const int wave = threadIdx.x >> 6;
  const int lane = threadIdx.x & 63;
  const int o = blockIdx.x * 4 + wave;     // 0 .. 128*512
  const int row = o >> 9;                  // / TWO_K
  const int col = o & (TWO_K - 1);
  const float4* __restrict__ a4 = (const float4*)(s1 + (size_t)row * TWO_N);
  const float4* __restrict__ c4 = (const float4*)C1last;
  const float4* __restrict__ b4 = (const float4*)(BT + (size_t)col * TWO_N);
  float acc = 0.f;
#pragma unroll
  for (int it = 0; it < 8; ++it) {
    const int idx = it * 64 + lane;
    const float4 av = a4[idx];
    const float4 cc = c4[idx];
    const float4 bv = b4[idx];
    const float r0 = cc.x * av.x - cc.y * av.y;
    const float i0 = cc.x * av.y + cc.y * av.x;
    const float r1 = cc.z * av.z - cc.w * av.w;
    const float i1 = cc.z * av.w + cc.w * av.z;
    acc = fmaf(r0, bv.x, acc);
    acc = fmaf(i0, bv.y, acc);
    acc = fmaf(r1, bv.z, acc);
    acc = fmaf(i1, bv.w, acc);
  }
#pragma unroll
  for (int s = 32; s >= 1; s >>= 1) acc += __shfl_xor(acc, s);
  if (lane == 0) C[o] = acc;
}

// ---------------- tail GEMM: one wave per output, A [M,K] f32, BT [N,K] f32 ----------------
__global__ __launch_bounds__(256) void k_tail(const float* __restrict__ A,
                                              const float* __restrict__ BT,
                                              float* __restrict__ C, int M, int N, int K) {
  const int wave = threadIdx.x >> 6;
  const int lane = threadIdx.x & 63;
  const int o = blockIdx.x * 4 + wave;
  if (o >= M * N) return;
  const int row = o / N;
  const int col = o - row * N;
  const float4* __restrict__ a4 = (const float4*)(A + (size_t)row * K);
  const float4* __restrict__ b4 = (const float4*)(BT + (size_t)col * K);
  float acc = 0.f;
  const int nit = K >> 8;
  for (int it = 0; it < nit; ++it) {
    const float4 av = a4[it * 64 + lane];
    const float4 bv = b4[it * 64 + lane];
    acc = fmaf(av.x, bv.x, acc);
    acc = fmaf(av.y, bv.y, acc);
    acc = fmaf(av.z, bv.z, acc);
    acc = fmaf(av.w, bv.w, acc);
  }
#pragma unroll
  for (int s = 32; s >= 1; s >>= 1) acc += __shfl_xor(acc, s);
  if (lane == 0) C[o] = acc;
}

// ---------------- weight packing ----------------
__global__ __launch_bounds__(256) void k_prep_in(const float* __restrict__ r, const float* __restrict__ im,
                                                 _Float16* __restrict__ dst) {
  const int gid = blockIdx.x * 256 + threadIdx.x;
  const int n = gid & (NN - 1);
  const int k = gid >> 10;
  const float rv = r[(size_t)k * NN + n], iv = im[(size_t)k * NN + n];
  const size_t base = (size_t)(2 * n) * TWO_K + 2 * k;
  dst[base] = (_Float16)rv;              dst[base + 1] = (_Float16)(-iv);
  dst[base + TWO_K] = (_Float16)iv;      dst[base + TWO_K + 1] = (_Float16)rv;
}
__global__ __launch_bounds__(256) void k_prep_out(const float* __restrict__ r, const float* __restrict__ im,
                                                  _Float16* __restrict__ dst) {
  const int gid = blockIdx.x * 256 + threadIdx.x;
  const int d = gid & (DD - 1);
  const int n = gid >> 8;
  const float rv = r[(size_t)n * DD + d], iv = im[(size_t)n * DD + d];
  const size_t base = (size_t)(2 * d) * TWO_N + 2 * n;
  dst[base] = (_Float16)rv;              dst[base + 1] = (_Float16)(-iv);
  dst[base + TWO_N] = (_Float16)iv;      dst[base + TWO_N + 1] = (_Float16)rv;
}
__global__ __launch_bounds__(256) void k_prep_wout1T(const float* __restrict__ r, const float* __restrict__ im,
                                                     float* __restrict__ dstT) {
  const int gid = blockIdx.x * 256 + threadIdx.x;
  const int n = gid & (NN - 1);
  const int d = gid >> 10;
  const float rv = r[(size_t)n * DD + d], iv = im[(size_t)n * DD + d];
  const size_t b0 = (size_t)(2 * d) * TWO_N + 2 * n;
  const size_t b1 = (size_t)(2 * d + 1) * TWO_N + 2 * n;
  dstT[b0] = rv;     dstT[b0 + 1] = -iv;
  dstT[b1] = iv;     dstT[b1 + 1] = rv;
}
__global__ __launch_bounds__(256) void k_prep_finT(const float* __restrict__ pr, const float* __restrict__ pi_,
                                                   float* __restrict__ dstT) {
  const int gid = blockIdx.x * 256 + threadIdx.x;
  const int d = gid & (DD - 1);
  const int s = gid >> 8;
  const float a = pr[(size_t)d * 256 + s], b = pi_[(size_t)d * 256 + s];
  dstT[(size_t)s * TWO_K + 2 * d] = a + b;
  dstT[(size_t)s * TWO_K + 2 * d + 1] = a - b;
}

extern "C" void kernel_launch(void* const* d_in, const int* in_sizes, int n_in,
                              void* d_out, int out_size, void* d_ws, size_t ws_size,
                              hipStream_t stream) {
  const int* ids      = (const int*)d_in[0];
  const float* emb    = (const float*)d_in[1];
  const float* win_r  = (const float*)d_in[2];
  const float* win_i  = (const float*)d_in[3];
  const float* wout_r = (const float*)d_in[4];
  const float* wout_i = (const float*)d_in[5];
  const float* omega  = (const float*)d_in[6];
  const float* outp_r = (const float*)d_in[7];
  const float* outp_i = (const float*)d_in[8];

  char* ws = (char*)d_ws;
  size_t off = 0;
  auto alloc = [&](size_t bytes) { void* p = ws + off; off += (bytes + 255) & ~(size_t)255; return p; };

  float2* R0     = (float2*)alloc((size_t)S_LEN * NN * 8);
  float2* D1     = (float2*)alloc((size_t)S_LEN * NN * 8);
  float2* C1last = (float2*)alloc((size_t)NN * 8);
  float2* ZS     = (float2*)alloc((size_t)BB * NN * 8);
  float* hstate  = (float*)alloc((size_t)BB * DD * 2 * 4);
  float* s1      = (float*)alloc((size_t)BB * TWO_N * 4);
  float* xt      = (float*)alloc((size_t)BB * TWO_K * 4);
  _Float16* BTin0  = (_Float16*)alloc((size_t)TWO_N * TWO_K * 2);
  _Float16* BTout0 = (_Float16*)alloc((size_t)TWO_K * TWO_N * 2);
  _Float16* BTin1  = (_Float16*)alloc((size_t)TWO_N * TWO_K * 2);
  float* Wout1T = (float*)alloc((size_t)TWO_K * TWO_N * 4);
  float* WfinT  = (float*)alloc((size_t)256 * TWO_K * 4);
  const size_t fixed = off;

  int CH = 1024;
  while (CH > 32) {
    size_t need = fixed + (size_t)CH * BB * 2 * (TWO_K + TWO_N) + 2 * 256;
    if (need <= ws_size) break;
    CH >>= 1;
  }
  _Float16* X0 = (_Float16*)alloc((size_t)CH * BB * TWO_K * 2);
  _Float16* VB = (_Float16*)alloc((size_t)CH * BB * TWO_N * 2);
  _Float16* Yc = X0;

  k_rot<<<2 * NN, 256, 0, stream>>>(omega, R0, D1, C1last);
  k_prep_in<<<DD * NN / 256, 256, 0, stream>>>(win_r, win_i, BTin0);
  k_prep_in<<<DD * NN / 256, 256, 0, stream>>>(win_r + (size_t)DD * NN, win_i + (size_t)DD * NN, BTin1);
  k_prep_out<<<NN * DD / 256, 256, 0, stream>>>(wout_r, wout_i, BTout0);
  k_prep_wout1T<<<NN * DD / 256, 256, 0, stream>>>(wout_r + (size_t)NN * DD, wout_i + (size_t)NN * DD, Wout1T);
  k_prep_finT<<<DD * 256 / 256, 256, 0, stream>>>(outp_r, outp_i, WfinT);

  const int nchunks = S_LEN / CH;
  for (int c = 0; c < nchunks; ++c) {
    const int t0 = c * CH;
    const int M = CH * BB;
    k_h<<<BB, 256, 0, stream>>>(ids, emb, hstate, X0, t0, CH);
    const int nb1 = (M / 128) * (TWO_N / 128);   // % 8 == 0
    k_gemm<<<nb1, 256, 0, stream>>>(X0, BTin0, VB, M, TWO_N, TWO_K, 4);
    k_scan<<<BB * (NN / 2) / 256, 256, 0, stream>>>(VB, R0 + (size_t)t0 * NN, ZS, CH, c == 0);
    const int nb2 = (M / 128) * (TWO_K / 128);   // % 8 == 0
    k_gemm<<<nb2, 256, 0, stream>>>(VB, BTout0, Yc, M, TWO_K, TWO_N, 2);
    k_gemm<<<nb1, 256, 0, stream>>>(Yc, BTin1, VB, M, TWO_N, TWO_K, 4);
    k_reduce<<<BB * (TWO_N / 4) / 256, 256, 0, stream>>>(VB, D1 + (size_t)t0 * NN, s1, CH, c == 0);
  }

  // xt[128, 512] = (C1last (*) s1) @ Wout1   (rotation fused into A-load)
  k_tail1<<<BB * TWO_K / 4, 256, 0, stream>>>(s1, C1last, Wout1T, xt);
  // out[128, 256] = xt[128, 512] @ Wfin
  k_tail<<<BB * 256 / 4, 256, 0, stream>>>(xt, WfinT, (float*)d_out, BB, 256, TWO_K);
}

// Round 15
// 1467.854 us; speedup vs baseline: 1.1920x; 1.0165x over previous
//
#include <hip/hip_runtime.h>

#define S_LEN 1024
#define BB 128
#define DD 256
#define NN 1024
#define TWO_K 512   // 2*DD
#define TWO_N 2048  // 2*NN

typedef _Float16 half8 __attribute__((ext_vector_type(8)));
typedef float f32x4 __attribute__((ext_vector_type(4)));

__device__ __forceinline__ float wrap2pi(float x) {
  float r = fmodf(x, 6.283185307179586f);
  if (r < 0.f) r += 6.283185307179586f;
  return r;
}
__device__ __forceinline__ int lut_index(float th) {
  float w = wrap2pi(th);
  return ((int)floorf(w * 651.8986469044033f)) & 4095;
}
// quantized phase as a fraction of a revolution (exact mod-4096 in revolutions)
__device__ __forceinline__ float q12(float th) {
  const float y = floorf(th * 651.8986469044033f) * 0.000244140625f;
  return y - floorf(y);
}

// ---------------- h recurrence -> X0 [CH*BB, 2*DD] f16 interleaved ----------------
__global__ __launch_bounds__(256) void k_h(const int* __restrict__ ids,
                                           const float* __restrict__ emb,
                                           float* __restrict__ hstate,
                                           _Float16* __restrict__ X0,
                                           int t0, int CH) {
  __shared__ __align__(16) float ebuf[2][8][2][256];
  __shared__ float tphi_s[1024];
  const int tid = threadIdx.x;
  const int lane = tid & 63;
  const int wv = tid >> 6;
  for (int i = tid; i < CH; i += 256)
    tphi_s[i] = wrap2pi((float)(t0 + i) * 1.618033988749895f);

  const int b = blockIdx.x;
  const int d = tid;
  const int* __restrict__ idrow = ids + b * S_LEN + t0;
  const int NST = CH >> 3;

#pragma unroll
  for (int q = 0; q < 2; ++q) {
    const int j = wv * 2 + q;
    const int id = idrow[j];
    const float* src = emb + (size_t)id * 512 + lane * 4;
    __builtin_amdgcn_global_load_lds((const __attribute__((address_space(1))) void*)src,
                                     (__attribute__((address_space(3))) void*)(&ebuf[0][j][0][0]), 16, 0, 0);
    __builtin_amdgcn_global_load_lds((const __attribute__((address_space(1))) void*)(src + 256),
                                     (__attribute__((address_space(3))) void*)(&ebuf[0][j][1][0]), 16, 0, 0);
  }

  float hr, hi;
  if (t0 == 0) { hr = 0.f; hi = 0.f; }
  else { float2 h = ((const float2*)hstate)[b * DD + d]; hr = h.x; hi = h.y; }

  int buf = 0;
  __syncthreads();

  for (int st = 0; st < NST; ++st) {
    if (st + 1 < NST) {
#pragma unroll
      for (int q = 0; q < 2; ++q) {
        const int j = wv * 2 + q;
        const int id = idrow[(st + 1) * 8 + j];
        const float* src = emb + (size_t)id * 512 + lane * 4;
        __builtin_amdgcn_global_load_lds((const __attribute__((address_space(1))) void*)src,
                                         (__attribute__((address_space(3))) void*)(&ebuf[buf ^ 1][j][0][0]), 16, 0, 0);
        __builtin_amdgcn_global_load_lds((const __attribute__((address_space(1))) void*)(src + 256),
                                         (__attribute__((address_space(3))) void*)(&ebuf[buf ^ 1][j][1][0]), 16, 0, 0);
      }
    }
    float rwl[8], bvt[8];
#pragma unroll
    for (int j = 0; j < 8; ++j) {
      const float w  = ebuf[buf][j][0][d];
      const float bv = ebuf[buf][j][1][d];
      rwl[j] = 1.0f / (1.f + fabsf(w));
      bvt[j] = bv + tphi_s[st * 8 + j];
    }
#pragma unroll
    for (int j = 0; j < 8; ++j) {
      const int tt = st * 8 + j;
      const float thr = fmaf(hr, rwl[j], bvt[j]);
      const float thi = fmaf(hi, rwl[j], bvt[j]);
      const float fr = q12(thr);
      const float fi = q12(thi);
      const float sr = __builtin_amdgcn_sinf(fr), cr = __builtin_amdgcn_cosf(fr);
      const float si = __builtin_amdgcn_sinf(fi), ci = __builtin_amdgcn_cosf(fi);
      hr = cr * ci - sr * si;
      hi = cr * si + sr * ci;
      union { unsigned int u; _Float16 h2[2]; } pk;
      pk.h2[0] = (_Float16)hr; pk.h2[1] = (_Float16)hi;
      *(((unsigned int*)(X0 + (size_t)(tt * BB + b) * TWO_K)) + d) = pk.u;
    }
    __syncthreads();
    buf ^= 1;
  }
  ((float2*)hstate)[b * DD + d] = make_float2(hr, hi);
}

// ---------------- rotation tables ----------------
// l==0: R0[t,n] per-step rotation; l==1: D1[t,n] conj prefix, C1last full prefix.
__global__ __launch_bounds__(256) void k_rot(const float* __restrict__ omega,
                                             float2* __restrict__ R0, float2* __restrict__ D1,
                                             float2* __restrict__ C1last) {
  const int blk = blockIdx.x;               // 0..2047
  const int l = blk >> 10, n = blk & (NN - 1);
  const int tid = threadIdx.x;
  const int lane = tid & 63;
  const int wid = tid >> 6;
  const float om = omega[l * NN + n];

  int idxv[4], pre[4];
  int own = 0;
  const int tb = tid * 4;
#pragma unroll
  for (int j = 0; j < 4; ++j) {
    idxv[j] = lut_index(om + (float)(tb + j) * 1.618033988749895f);
    own += idxv[j];
    pre[j] = own;
  }
  if (l == 0) {
#pragma unroll
    for (int j = 0; j < 4; ++j) {
      const int t = tb + j;
      const float s = sinf(0.0015339807878856412f * (float)idxv[j]);
      const float c = cosf(0.0015339807878856412f * (float)idxv[j]);
      R0[t * NN + n] = make_float2(c, s);
    }
    return;  // block-uniform branch
  }
  int v = own;
#pragma unroll
  for (int off = 1; off < 64; off <<= 1) {
    int u = __shfl_up(v, off);
    if (lane >= off) v += u;
  }
  __shared__ int wsum[4];
  if (lane == 63) wsum[wid] = v;
  __syncthreads();
  int woff = 0;
#pragma unroll
  for (int w = 0; w < 4; ++w) woff += (w < wid) ? wsum[w] : 0;
  const int excl = woff + v - own;

#pragma unroll
  for (int j = 0; j < 4; ++j) {
    const int t = tb + j;
    const int idx = (excl + pre[j]) & 4095;
    const float s = sinf(0.0015339807878856412f * (float)idx);
    const float c = cosf(0.0015339807878856412f * (float)idx);
    D1[t * NN + n] = make_float2(c, -s);
    if (t == S_LEN - 1) C1last[n] = make_float2(c, s);
  }
}

// ---------------- f16 MFMA GEMM (R14): 128x128 tile, BK=64, pure ----------------
__global__ __launch_bounds__(256, 2) void k_gemm(const _Float16* __restrict__ A,
                                                 const _Float16* __restrict__ BT,
                                                 _Float16* __restrict__ C,
                                                 int M, int N, int K, int nxlog2) {
  __shared__ __align__(16) _Float16 As[128 * 64];
  __shared__ __align__(16) _Float16 Bs[128 * 64];
  const int tid = threadIdx.x;
  const int lane = tid & 63;
  const int wave = tid >> 6;
  const int wm = wave >> 1;
  const int wn = wave & 1;

  const int cpx = gridDim.x >> 3;
  const int bid = blockIdx.x;
  const int swz = (bid & 7) * cpx + (bid >> 3);
  const int bx = swz & ((1 << nxlog2) - 1);
  const int by = swz >> nxlog2;
  const int m0 = by * 128;
  const int n0 = bx * 128;

  const int srow = lane >> 3;
  const int schunk = (lane & 7) ^ srow;

  f32x4 acc[4][4] = {};

  for (int kt = 0; kt < K; kt += 64) {
#pragma unroll
    for (int j = 0; j < 4; ++j) {
      const int c = wave * 4 + j;
      const int row = c * 8 + srow;
      const _Float16* srcA = A + (size_t)(m0 + row) * K + kt + schunk * 8;
      __builtin_amdgcn_global_load_lds((const __attribute__((address_space(1))) void*)srcA,
                                       (__attribute__((address_space(3))) void*)(As + c * 512), 16, 0, 0);
      const _Float16* srcB = BT + (size_t)(n0 + row) * K + kt + schunk * 8;
      __builtin_amdgcn_global_load_lds((const __attribute__((address_space(1))) void*)srcB,
                                       (__attribute__((address_space(3))) void*)(Bs + c * 512), 16, 0, 0);
    }
    __syncthreads();
#pragma unroll
    for (int ks = 0; ks < 2; ++ks) {
      half8 af[4], bf[4];
#pragma unroll
      for (int mr = 0; mr < 4; ++mr) {
        const int ar = wm * 64 + mr * 16 + (lane & 15);
        const int p = ((ks * 4) + (lane >> 4)) ^ (ar & 7);
        af[mr] = *(const half8*)(As + ar * 64 + p * 8);
      }
#pragma unroll
      for (int nr = 0; nr < 4; ++nr) {
        const int br = wn * 64 + nr * 16 + (lane & 15);
        const int p = ((ks * 4) + (lane >> 4)) ^ (br & 7);
        bf[nr] = *(const half8*)(Bs + br * 64 + p * 8);
      }
#pragma unroll
      for (int mr = 0; mr < 4; ++mr)
#pragma unroll
        for (int nr = 0; nr < 4; ++nr)
          acc[mr][nr] = __builtin_amdgcn_mfma_f32_16x16x32_f16(af[mr], bf[nr], acc[mr][nr], 0, 0, 0);
    }
    __syncthreads();
  }

#pragma unroll
  for (int mr = 0; mr < 4; ++mr)
#pragma unroll
    for (int nr = 0; nr < 4; ++nr) {
      const int col = n0 + wn * 64 + nr * 16 + (lane & 15);
      const int rbase = m0 + wm * 64 + mr * 16 + ((lane >> 4) << 2);
#pragma unroll
      for (int j = 0; j < 4; ++j)
        C[(size_t)(rbase + j) * N + col] = (_Float16)acc[mr][nr][j];
    }
}

// ---------------- recurrence scan over t (in place): w_t = r_t (*) w_{t-1} + u_t ----------------
// 1 complex per thread (131072 threads) for TLP; SUF=8 register double-buffer.
#define SUF 8
__global__ __launch_bounds__(256) void k_scan(_Float16* __restrict__ V,          // [CH*BB, TWO_N]
                                              const float2* __restrict__ R0c,    // [CH, NN] at t0
                                              float2* __restrict__ ZS, int CH, int first) {
  const int gid = blockIdx.x * 256 + threadIdx.x;  // b*NN + n
  const int n = gid & (NN - 1);
  const int b = gid >> 10;
  float zr, zi;
  if (first) { zr = 0.f; zi = 0.f; }
  else { const float2 z = ZS[gid]; zr = z.x; zi = z.y; }
  const unsigned int* __restrict__ Vu = (const unsigned int*)V;
  unsigned int* __restrict__ Vw = (unsigned int*)V;
  unsigned int vb[SUF], vn[SUF];
  float2 cb[SUF], cn[SUF];
#pragma unroll
  for (int j = 0; j < SUF; ++j) {
    vb[j] = Vu[(size_t)(j * BB + b) * (TWO_N / 2) + n];
    cb[j] = R0c[(size_t)j * NN + n];
  }
  for (int st = 0; st < CH; st += SUF) {
    const bool more = (st + SUF) < CH;
    if (more) {
#pragma unroll
      for (int j = 0; j < SUF; ++j) {
        vn[j] = Vu[(size_t)((st + SUF + j) * BB + b) * (TWO_N / 2) + n];
        cn[j] = R0c[(size_t)(st + SUF + j) * NN + n];
      }
    }
#pragma unroll
    for (int j = 0; j < SUF; ++j) {
      union { unsigned int u; _Float16 h2[2]; } a;
      a.u = vb[j];
      const float2 cc = cb[j];
      const float wr = cc.x * zr - cc.y * zi + (float)a.h2[0];
      const float wi = cc.x * zi + cc.y * zr + (float)a.h2[1];
      zr = wr; zi = wi;
      a.h2[0] = (_Float16)zr; a.h2[1] = (_Float16)zi;
      Vw[(size_t)((st + j) * BB + b) * (TWO_N / 2) + n] = a.u;
    }
#pragma unroll
    for (int j = 0; j < SUF; ++j) { vb[j] = vn[j]; cb[j] = cn[j]; }
  }
  ZS[gid] = make_float2(zr, zi);
}

// ---------------- fused rotate+reduce over t: s1 += D1[t] (*) u[t]; 1 complex/thread ----------------
__global__ __launch_bounds__(256) void k_reduce(const _Float16* __restrict__ U,  // [CH*BB, TWO_N]
                                                const float2* __restrict__ D1c, // [CH, NN] at t0
                                                float* __restrict__ s1, int CH, int first) {
  const int gid = blockIdx.x * 256 + threadIdx.x;  // b*NN + n
  const int n = gid & (NN - 1);
  const int b = gid >> 10;
  float ar, ai;
  if (first) { ar = 0.f; ai = 0.f; }
  else { const float2 a = ((const float2*)s1)[gid & (NN - 1) | 0, 0], z = *(const float2*)(s1 + (size_t)b * TWO_N + 2 * n); ar = z.x; ai = z.y; }
  const unsigned int* __restrict__ Uu = (const unsigned int*)U;
  unsigned int vb[SUF], vn[SUF];
  float2 db[SUF], dn[SUF];
#pragma unroll
  for (int j = 0; j < SUF; ++j) {
    vb[j] = Uu[(size_t)(j * BB + b) * (TWO_N / 2) + n];
    db[j] = D1c[(size_t)j * NN + n];
  }
  for (int st = 0; st < CH; st += SUF) {
    const bool more = (st + SUF) < CH;
    if (more) {
#pragma unroll
      for (int j = 0; j < SUF; ++j) {
        vn[j] = Uu[(size_t)((st + SUF + j) * BB + b) * (TWO_N / 2) + n];
        dn[j] = D1c[(size_t)(st + SUF + j) * NN + n];
      }
    }
#pragma unroll
    for (int j = 0; j < SUF; ++j) {
      union { unsigned int u; _Float16 h2[2]; } a;
      a.u = vb[j];
      const float u0 = (float)a.h2[0], u1 = (float)a.h2[1];
      const float2 d = db[j];
      ar += d.x * u0 - d.y * u1;
      ai += d.x * u1 + d.y * u0;
    }
#pragma unroll
    for (int j = 0; j < SUF; ++j) { vb[j] = vn[j]; db[j] = dn[j]; }
  }
  *(float2*)(s1 + (size_t)b * TWO_N + 2 * n) = make_float2(ar, ai);
}

// ---------------- tail GEMM 1: xt = rot(s1) @ Wout1, rotation fused into A-load ----------------
__global__ __launch_bounds__(256) void k_tail1(const float* __restrict__ s1,
                                               const float2* __restrict__ C1last,
                                               const float* __restrict__ BT,   // [TWO_K, TWO_N]
                                               float* __restrict__ C) {
  const int wave = threadIdx.x >> 6;
  const int lane = threadIdx.x & 63;
  const int o = blockIdx.x * 4 + wave;
  const int row = o >> 9;
  const int col = o & (TWO_K - 1);
  const float4* __restrict__ a4 = (const float4*)(s1 + (size_t)row * TWO_N);
  const float4* __restrict__ c4 = (const float4*)C1last;
  const float4* __restrict__ b4 = (const float4*)(BT + (size_t)col * TWO_N);
  float acc = 0.f;
#pragma unroll
  for (int it = 0; it < 8; ++it) {
    const int idx = it * 64 + lane;
    const float4 av = a4[idx];
    const float4 cc = c4[idx];
    const float4 bv = b4[idx];
    const float r0 = cc.x * av.x - cc.y * av.y;
    const float i0 = cc.x * av.y + cc.y * av.x;
    const float r1 = cc.z * av.z - cc.w * av.w;
    const float i1 = cc.z * av.w + cc.w * av.z;
    acc = fmaf(r0, bv.x, acc);
    acc = fmaf(i0, bv.y, acc);
    acc = fmaf(r1, bv.z, acc);
    acc = fmaf(i1, bv.w, acc);
  }
#pragma unroll
  for (int s = 32; s >= 1; s >>= 1) acc += __shfl_xor(acc, s);
  if (lane == 0) C[o] = acc;
}

// ---------------- tail GEMM: one wave per output ----------------
__global__ __launch_bounds__(256) void k_tail(const float* __restrict__ A,
                                              const float* __restrict__ BT,
                                              float* __restrict__ C, int M, int N, int K) {
  const int wave = threadIdx.x >> 6;
  const int lane = threadIdx.x & 63;
  const int o = blockIdx.x * 4 + wave;
  if (o >= M * N) return;
  const int row = o / N;
  const int col = o - row * N;
  const float4* __restrict__ a4 = (const float4*)(A + (size_t)row * K);
  const float4* __restrict__ b4 = (const float4*)(BT + (size_t)col * K);
  float acc = 0.f;
  const int nit = K >> 8;
  for (int it = 0; it < nit; ++it) {
    const float4 av = a4[it * 64 + lane];
    const float4 bv = b4[it * 64 + lane];
    acc = fmaf(av.x, bv.x, acc);
    acc = fmaf(av.y, bv.y, acc);
    acc = fmaf(av.z, bv.z, acc);
    acc = fmaf(av.w, bv.w, acc);
  }
#pragma unroll
  for (int s = 32; s >= 1; s >>= 1) acc += __shfl_xor(acc, s);
  if (lane == 0) C[o] = acc;
}

// ---------------- merged weight packing (dispatch ranges by blockIdx) ----------------
__global__ __launch_bounds__(256) void k_prep_all(const float* __restrict__ win_r, const float* __restrict__ win_i,
                                                  const float* __restrict__ wout_r, const float* __restrict__ wout_i,
                                                  const float* __restrict__ outp_r, const float* __restrict__ outp_i,
                                                  _Float16* __restrict__ BTin0, _Float16* __restrict__ BTin1,
                                                  _Float16* __restrict__ BTout0, float* __restrict__ Wout1T,
                                                  float* __restrict__ WfinT) {
  const int blk = blockIdx.x;
  const int tid = threadIdx.x;
  if (blk < 2048) {  // BTin0 / BTin1 (transposed interleaved-complex from win[l])
    const int l = blk >> 10;
    const int gid = (blk & 1023) * 256 + tid;   // k*NN + n over DD*NN
    const int n = gid & (NN - 1);
    const int k = gid >> 10;
    const float* r  = win_r + (size_t)l * DD * NN;
    const float* im = win_i + (size_t)l * DD * NN;
    _Float16* dst = l ? BTin1 : BTin0;
    const float rv = r[(size_t)k * NN + n], iv = im[(size_t)k * NN + n];
    const size_t base = (size_t)(2 * n) * TWO_K + 2 * k;
    dst[base] = (_Float16)rv;              dst[base + 1] = (_Float16)(-iv);
    dst[base + TWO_K] = (_Float16)iv;      dst[base + TWO_K + 1] = (_Float16)rv;
  } else if (blk < 3072) {  // BTout0 from wout[0]
    const int gid = (blk - 2048) * 256 + tid;   // n*DD + d
    const int d = gid & (DD - 1);
    const int n = gid >> 8;
    const float rv = wout_r[(size_t)n * DD + d], iv = wout_i[(size_t)n * DD + d];
    const size_t base = (size_t)(2 * d) * TWO_N + 2 * n;
    BTout0[base] = (_Float16)rv;              BTout0[base + 1] = (_Float16)(-iv);
    BTout0[base + TWO_N] = (_Float16)iv;      BTout0[base + TWO_N + 1] = (_Float16)rv;
  } else if (blk < 4096) {  // Wout1T from wout[1]
    const int gid = (blk - 3072) * 256 + tid;   // d*NN + n
    const int n = gid & (NN - 1);
    const int d = gid >> 10;
    const float* r  = wout_r + (size_t)NN * DD;
    const float* im = wout_i + (size_t)NN * DD;
    const float rv = r[(size_t)n * DD + d], iv = im[(size_t)n * DD + d];
    const size_t b0 = (size_t)(2 * d) * TWO_N + 2 * n;
    const size_t b1 = (size_t)(2 * d + 1) * TWO_N + 2 * n;
    Wout1T[b0] = rv;     Wout1T[b0 + 1] = -iv;
    Wout1T[b1] = iv;     Wout1T[b1 + 1] = rv;
  } else {  // WfinT
    const int gid = (blk - 4096) * 256 + tid;   // s*DD + d
    const int d = gid & (DD - 1);
    const int s = gid >> 8;
    const float a = outp_r[(size_t)d * 256 + s], b = outp_i[(size_t)d * 256 + s];
    WfinT[(size_t)s * TWO_K + 2 * d] = a + b;
    WfinT[(size_t)s * TWO_K + 2 * d + 1] = a - b;
  }
}

extern "C" void kernel_launch(void* const* d_in, const int* in_sizes, int n_in,
                              void* d_out, int out_size, void* d_ws, size_t ws_size,
                              hipStream_t stream) {
  const int* ids      = (const int*)d_in[0];
  const float* emb    = (const float*)d_in[1];
  const float* win_r  = (const float*)d_in[2];
  const float* win_i  = (const float*)d_in[3];
  const float* wout_r = (const float*)d_in[4];
  const float* wout_i = (const float*)d_in[5];
  const float* omega  = (const float*)d_in[6];
  const float* outp_r = (const float*)d_in[7];
  const float* outp_i = (const float*)d_in[8];

  char* ws = (char*)d_ws;
  size_t off = 0;
  auto alloc = [&](size_t bytes) { void* p = ws + off; off += (bytes + 255) & ~(size_t)255; return p; };

  float2* R0     = (float2*)alloc((size_t)S_LEN * NN * 8);
  float2* D1     = (float2*)alloc((size_t)S_LEN * NN * 8);
  float2* C1last = (float2*)alloc((size_t)NN * 8);
  float2* ZS     = (float2*)alloc((size_t)BB * NN * 8);
  float* hstate  = (float*)alloc((size_t)BB * DD * 2 * 4);
  float* s1      = (float*)alloc((size_t)BB * TWO_N * 4);
  float* xt      = (float*)alloc((size_t)BB * TWO_K * 4);
  _Float16* BTin0  = (_Float16*)alloc((size_t)TWO_N * TWO_K * 2);
  _Float16* BTout0 = (_Float16*)alloc((size_t)TWO_K * TWO_N * 2);
  _Float16* BTin1  = (_Float16*)alloc((size_t)TWO_N * TWO_K * 2);
  float* Wout1T = (float*)alloc((size_t)TWO_K * TWO_N * 4);
  float* WfinT  = (float*)alloc((size_t)256 * TWO_K * 4);
  const size_t fixed = off;

  int CH = 1024;
  while (CH > 32) {
    size_t need = fixed + (size_t)CH * BB * 2 * (TWO_K + TWO_N) + 2 * 256;
    if (need <= ws_size) break;
    CH >>= 1;
  }
  _Float16* X0 = (_Float16*)alloc((size_t)CH * BB * TWO_K * 2);
  _Float16* VB = (_Float16*)alloc((size_t)CH * BB * TWO_N * 2);
  _Float16* Yc = X0;

  k_rot<<<2 * NN, 256, 0, stream>>>(omega, R0, D1, C1last);
  k_prep_all<<<4352, 256, 0, stream>>>(win_r, win_i, wout_r, wout_i, outp_r, outp_i,
                                       BTin0, BTin1, BTout0, Wout1T, WfinT);

  const int nchunks = S_LEN / CH;
  for (int c = 0; c < nchunks; ++c) {
    const int t0 = c * CH;
    const int M = CH * BB;
    k_h<<<BB, 256, 0, stream>>>(ids, emb, hstate, X0, t0, CH);
    const int nb1 = (M / 128) * (TWO_N / 128);   // % 8 == 0
    k_gemm<<<nb1, 256, 0, stream>>>(X0, BTin0, VB, M, TWO_N, TWO_K, 4);
    k_scan<<<BB * NN / 256, 256, 0, stream>>>(VB, R0 + (size_t)t0 * NN, ZS, CH, c == 0);
    const int nb2 = (M / 128) * (TWO_K / 128);   // % 8 == 0
    k_gemm<<<nb2, 256, 0, stream>>>(VB, BTout0, Yc, M, TWO_K, TWO_N, 2);
    k_gemm<<<nb1, 256, 0, stream>>>(Yc, BTin1, VB, M, TWO_N, TWO_K, 4);
    k_reduce<<<BB * NN / 256, 256, 0, stream>>>(VB, D1 + (size_t)t0 * NN, s1, CH, c == 0);
  }

  // xt[128, 512] = (C1last (*) s1) @ Wout1   (rotation fused into A-load)
  k_tail1<<<BB * TWO_K / 4, 256, 0, stream>>>(s1, C1last, Wout1T, xt);
  // out[128, 256] = xt[128, 512] @ Wfin
  k_tail<<<BB * 256 / 4, 256, 0, stream>>>(xt, WfinT, (float*)d_out, BB, 256, TWO_K);
}